// Round 1
// baseline (164.594 us; speedup 1.0000x reference)
//
#include <hip/hip_runtime.h>

#define C 96
#define BKT_SHIFT 9
#define BKT_SIZE 512    // nodes per bucket
#define CAP 10240       // per-bucket csr capacity (bucket mean 8163)
#define EB 2048         // edges per sort item
typedef unsigned char u8;
typedef unsigned short u16;
typedef unsigned int u32;
typedef __attribute__((ext_vector_type(8))) short short8;
typedef __attribute__((ext_vector_type(4))) float floatx4;
typedef __attribute__((ext_vector_type(2))) float floatx2;

__device__ inline u16 f2bf(float f) {
    union { float f; u32 u; } v; v.f = f;
    u32 r = v.u + 0x7fff + ((v.u >> 16) & 1);   // RNE
    return (u16)(r >> 16);
}
__device__ inline u32 pk4_fp8(float a, float b, float c, float d) {
    u32 w = 0;
    w = __builtin_amdgcn_cvt_pk_fp8_f32(a, b, w, false);
    w = __builtin_amdgcn_cvt_pk_fp8_f32(c, d, w, true);
    return w;
}
__device__ inline u8 f2fp8(float a) {
    return (u8)(__builtin_amdgcn_cvt_pk_fp8_f32(a, a, 0, false) & 0xff);
}

// ---------------------------------------------------------------------------
// binA (sort only, 391 blocks): counting-sort 2048 edges into 128 dst-buckets
// in LDS, flush PRIVATE per-item stage region (coalesced, no global atomics)
// + per-(item,bucket) count/offset tables.
__global__ __launch_bounds__(256) void binA_kernel(const int* __restrict__ src,
                                                   const int* __restrict__ dst,
                                                   int* __restrict__ blk_cnt,
                                                   int* __restrict__ blk_off,
                                                   u32* __restrict__ stage, int E) {
    __shared__ u32 s_word[EB];
    __shared__ int s_cnt[128];
    __shared__ int s_inc[128];
    int bid = blockIdx.x;
    int t = threadIdx.x;
    int e0 = bid * EB;
    int cnt_here = min(EB, E - e0);

    for (int i = t; i < 128; i += 256) s_cnt[i] = 0;
    __syncthreads();

    int my_src[EB / 256], my_dl[EB / 256], my_b[EB / 256], my_rank[EB / 256];
    int nmine = 0;
#pragma unroll
    for (int k = 0; k < EB / 256; k++) {
        int i = t + k * 256;
        if (i < cnt_here) {
            int s = src[e0 + i], d = dst[e0 + i];
            int b = d >> BKT_SHIFT;
            my_src[nmine] = s;
            my_dl[nmine] = d & (BKT_SIZE - 1);
            my_b[nmine] = b;
            my_rank[nmine] = atomicAdd(&s_cnt[b], 1);
            nmine++;
        }
    }
    __syncthreads();

    if (t < 128) s_inc[t] = s_cnt[t];
    __syncthreads();
    for (int off = 1; off < 128; off <<= 1) {
        int x2 = (t >= off && t < 128) ? s_inc[t - off] : 0;
        __syncthreads();
        if (t < 128) s_inc[t] += x2;
        __syncthreads();
    }
    if (t < 128) {
        blk_cnt[bid * 128 + t] = s_cnt[t];
        blk_off[bid * 128 + t] = s_inc[t] - s_cnt[t];
    }

    for (int k = 0; k < nmine; k++) {
        int b = my_b[k];
        int slot = (s_inc[b] - s_cnt[b]) + my_rank[k];
        s_word[slot] = ((u32)my_dl[k] << 16) | (u32)my_src[k];
    }
    __syncthreads();

    for (int i = t; i < cnt_here; i += 256) stage[(size_t)bid * EB + i] = s_word[i];
}

// ---------------------------------------------------------------------------
// binB: blocks [0,nbkt) build per-bucket CSR (run-walk count -> LDS scan(512)
// -> deg/row_off -> csr scatter). Blocks [nbkt,nbkt+CX): x -> bf16 + fp8
// (independent of binA; fills CUs idle during latency-bound bucket walks).
// Last 4 blocks: W -> bf16 transpose.
__global__ __launch_bounds__(256) void binB_kernel(const u32* __restrict__ stage,
                                                   const int* __restrict__ blk_cnt,
                                                   const int* __restrict__ blk_off,
                                                   int* __restrict__ deg,
                                                   int* __restrict__ row_off,
                                                   u16* __restrict__ csr, int N, int DB,
                                                   int nbkt,
                                                   const float* __restrict__ x,
                                                   u16* __restrict__ xb,
                                                   u8* __restrict__ xf8, int n16, int CX,
                                                   const float* W0, const float* W1,
                                                   const float* W2, const float* W3,
                                                   u16* T0, u16* T1, u16* T2, u16* T3) {
    int bid = blockIdx.x;
    int t = threadIdx.x;
    if (bid >= nbkt) {
        if (bid < nbkt + CX) {
            int i = (bid - nbkt) * 256 + t;
            if (i >= n16) return;
            const float4* p = (const float4*)x + (size_t)i * 4;
            float4 a = p[0], b = p[1], c = p[2], d = p[3];
            short8 o0, o1;
            o0[0] = (short)f2bf(a.x); o0[1] = (short)f2bf(a.y);
            o0[2] = (short)f2bf(a.z); o0[3] = (short)f2bf(a.w);
            o0[4] = (short)f2bf(b.x); o0[5] = (short)f2bf(b.y);
            o0[6] = (short)f2bf(b.z); o0[7] = (short)f2bf(b.w);
            o1[0] = (short)f2bf(c.x); o1[1] = (short)f2bf(c.y);
            o1[2] = (short)f2bf(c.z); o1[3] = (short)f2bf(c.w);
            o1[4] = (short)f2bf(d.x); o1[5] = (short)f2bf(d.y);
            o1[6] = (short)f2bf(d.z); o1[7] = (short)f2bf(d.w);
            *(short8*)(xb + (size_t)i * 16) = o0;
            *(short8*)(xb + (size_t)i * 16 + 8) = o1;
            uint4 f8;
            f8.x = pk4_fp8(a.x, a.y, a.z, a.w);
            f8.y = pk4_fp8(b.x, b.y, b.z, b.w);
            f8.z = pk4_fp8(c.x, c.y, c.z, c.w);
            f8.w = pk4_fp8(d.x, d.y, d.z, d.w);
            *(uint4*)(xf8 + (size_t)i * 16) = f8;
        } else {
            int w = bid - nbkt - CX;
            const float* W = w == 0 ? W0 : w == 1 ? W1 : w == 2 ? W2 : W3;
            u16* T = w == 0 ? T0 : w == 1 ? T1 : w == 2 ? T2 : T3;
            for (int i = t; i < C * C; i += 256) {
                int k = i / C, n = i - k * C;
                T[n * C + k] = f2bf(W[i]);
            }
        }
        return;
    }

    __shared__ int cnt[BKT_SIZE];
    __shared__ int cur[BKT_SIZE];
    __shared__ int ssum[256];
    int b = bid;
    int n0 = b << BKT_SHIFT;
    int nn = min(BKT_SIZE, N - n0);
    int s0 = b * CAP;

    for (int i = t; i < BKT_SIZE; i += 256) cnt[i] = 0;
    __syncthreads();

    for (int i = t; i < DB; i += 256) {
        int len = blk_cnt[i * 128 + b];
        const u32* run = stage + (size_t)i * EB + blk_off[i * 128 + b];
        for (int j = 0; j < len; j++) atomicAdd(&cnt[run[j] >> 16], 1);
    }
    __syncthreads();

    int a0 = cnt[2 * t], a1 = cnt[2 * t + 1];
    ssum[t] = a0 + a1;
    __syncthreads();
    for (int off = 1; off < 256; off <<= 1) {
        int x2 = (t >= off) ? ssum[t - off] : 0;
        __syncthreads();
        ssum[t] += x2;
        __syncthreads();
    }
    int excl = ssum[t] - (a0 + a1);
    if (2 * t < nn) { deg[n0 + 2 * t] = a0; row_off[n0 + 2 * t] = s0 + excl; }
    if (2 * t + 1 < nn) { deg[n0 + 2 * t + 1] = a1; row_off[n0 + 2 * t + 1] = s0 + excl + a0; }
    __syncthreads();
    cur[2 * t] = s0 + excl;
    cur[2 * t + 1] = s0 + excl + a0;
    __syncthreads();

    for (int i = t; i < DB; i += 256) {
        int len = blk_cnt[i * 128 + b];
        const u32* run = stage + (size_t)i * EB + blk_off[i * 128 + b];
        for (int j = 0; j < len; j++) {
            u32 w = run[j];
            int p = atomicAdd(&cur[w >> 16], 1);
            csr[p] = (u16)(w & 0xffffu);
        }
    }
}

// ---------------------------------------------------------------------------
// Fused layer: Y = (RELU?)(mean_agg(X)@WA + X@WR + BIAS) for 64 nodes/block.
// Phase 1: fp8 gather, software-pipelined. NEW: aligned-slice partition —
// lane q of a node-quad reads bytes [16q,16q+16) + [64+8q,72+8q) of the 96 B
// row => one dwordx4 + one dwordx2 per edge-lane (8 loads/edge vs 12).
// Phase 2: dual MFMA. Epilogue: line-coalesced LDS staging -> contiguous
// 16 B/lane slab writes (no write-allocate).
template <bool RELU, bool WF8, typename OT>
__global__ __launch_bounds__(256, 4) void layer_kernel(const u16* __restrict__ Xbf,
                                                       const u8* __restrict__ Xf8,
                                                       const int* __restrict__ row_off,
                                                       const int* __restrict__ deg,
                                                       const u16* __restrict__ csr,
                                                       const u16* __restrict__ WTA,
                                                       const u16* __restrict__ WTR,
                                                       const float* __restrict__ BIAS,
                                                       OT* __restrict__ Y,
                                                       u8* __restrict__ Yf8, int n) {
    __shared__ u16 sA[64 * 104];   // gather tile; reused as output staging
    __shared__ int s_dg[64];
    __shared__ int s_perm[64];
    const int t = threadIdx.x;
    const int row0 = blockIdx.x * 64;

    // Phase 0: degree-rank permutation
    if (t < 64) {
        int node = row0 + t;
        s_dg[t] = (node < n) ? deg[node] : 0;
    }
    __syncthreads();
    if (t < 64) {
        int di = s_dg[t];
        int r = 0;
#pragma unroll 8
        for (int j = 0; j < 64; j++) {
            int dj = s_dg[j];
            r += (dj < di) || (dj == di && j < t);
        }
        s_perm[r] = t;
    }
    __syncthreads();

    // Phase 1: fp8 gather-mean (4 lanes/node, 24ch each, pipelined quads)
    // lane q owns channels [16q,16q+16) (acc[0..15]) and [64+8q,72+8q) (acc[16..23])
    {
        int nl = s_perm[t >> 2];
        int node = row0 + nl;
        int q = t & 3;
        float acc[24];
#pragma unroll
        for (int i = 0; i < 24; i++) acc[i] = 0.f;
        int d = 0, start = 0;
        if (node < n) { start = row_off[node]; d = s_dg[nl]; }
        const int off4 = q * 16;        // dwordx4 slice offset
        const int off2 = 64 + q * 8;    // dwordx2 slice offset

        int j = 0;
        if (d >= 4) {
            int si[4];
#pragma unroll
            for (int k = 0; k < 4; k++) si[k] = csr[start + k];
            for (; j + 8 <= d; j += 4) {
                uint4 va[4];
                uint2 vb[4];
#pragma unroll
                for (int k = 0; k < 4; k++) {
                    const u8* p = Xf8 + (size_t)si[k] * 96;
                    va[k] = *(const uint4*)(p + off4);
                    vb[k] = *(const uint2*)(p + off2);
                }
                int sn[4];    // prefetch next quad's indices before consuming
#pragma unroll
                for (int k = 0; k < 4; k++) sn[k] = csr[start + j + 4 + k];
#pragma unroll
                for (int k = 0; k < 4; k++) {
                    u32 ws[6] = {va[k].x, va[k].y, va[k].z,
                                 va[k].w, vb[k].x, vb[k].y};
#pragma unroll
                    for (int i = 0; i < 6; i++) {
                        floatx2 lo = __builtin_amdgcn_cvt_pk_f32_fp8(ws[i], false);
                        floatx2 hi = __builtin_amdgcn_cvt_pk_f32_fp8(ws[i], true);
                        acc[4 * i]     += lo[0];
                        acc[4 * i + 1] += lo[1];
                        acc[4 * i + 2] += hi[0];
                        acc[4 * i + 3] += hi[1];
                    }
                }
#pragma unroll
                for (int k = 0; k < 4; k++) si[k] = sn[k];
            }
            {   // drain the in-flight quad
                uint4 va[4];
                uint2 vb[4];
#pragma unroll
                for (int k = 0; k < 4; k++) {
                    const u8* p = Xf8 + (size_t)si[k] * 96;
                    va[k] = *(const uint4*)(p + off4);
                    vb[k] = *(const uint2*)(p + off2);
                }
#pragma unroll
                for (int k = 0; k < 4; k++) {
                    u32 ws[6] = {va[k].x, va[k].y, va[k].z,
                                 va[k].w, vb[k].x, vb[k].y};
#pragma unroll
                    for (int i = 0; i < 6; i++) {
                        floatx2 lo = __builtin_amdgcn_cvt_pk_f32_fp8(ws[i], false);
                        floatx2 hi = __builtin_amdgcn_cvt_pk_f32_fp8(ws[i], true);
                        acc[4 * i]     += lo[0];
                        acc[4 * i + 1] += lo[1];
                        acc[4 * i + 2] += hi[0];
                        acc[4 * i + 3] += hi[1];
                    }
                }
                j += 4;
            }
        }
        for (; j < d; j++) {
            const u8* p = Xf8 + (size_t)csr[start + j] * 96;
            uint4 va = *(const uint4*)(p + off4);
            uint2 vb = *(const uint2*)(p + off2);
            u32 ws[6] = {va.x, va.y, va.z, va.w, vb.x, vb.y};
#pragma unroll
            for (int i = 0; i < 6; i++) {
                floatx2 lo = __builtin_amdgcn_cvt_pk_f32_fp8(ws[i], false);
                floatx2 hi = __builtin_amdgcn_cvt_pk_f32_fp8(ws[i], true);
                acc[4 * i]     += lo[0];
                acc[4 * i + 1] += lo[1];
                acc[4 * i + 2] += hi[0];
                acc[4 * i + 3] += hi[1];
            }
        }
        float inv = 1.0f / fmaxf((float)d, 1.0f);
        u16* dl = sA + nl * 104;
        short8 o0, o1, o2;
#pragma unroll
        for (int i = 0; i < 8; i++) {
            o0[i] = (short)f2bf(acc[i] * inv);
            o1[i] = (short)f2bf(acc[8 + i] * inv);
            o2[i] = (short)f2bf(acc[16 + i] * inv);
        }
        *(short8*)(dl + q * 16) = o0;          // channels 16q..16q+7
        *(short8*)(dl + q * 16 + 8) = o1;      // channels 16q+8..16q+15
        *(short8*)(dl + 64 + q * 8) = o2;      // channels 64+8q..64+8q+7
    }
    __syncthreads();

    // Phase 2: dual MFMA GEMM
    const int lane = t & 63;
    const int w = t >> 6;
    const int quad = lane >> 4;
    const int l16 = lane & 15;
    const int r0 = row0 + w * 16;

    floatx4 acc6[6];
#pragma unroll
    for (int i = 0; i < 6; i++) acc6[i] = (floatx4){0.f, 0.f, 0.f, 0.f};

    {   // A-path: aggregated tile from LDS
        const u16* Ap = sA + (w * 16 + l16) * 104 + quad * 8;
        const u16* Wp = WTA + l16 * C + quad * 8;
#pragma unroll
        for (int ks = 0; ks < 3; ks++) {
            short8 a = *(const short8*)(Ap + ks * 32);
#pragma unroll
            for (int nt = 0; nt < 6; nt++) {
                short8 b = *(const short8*)(Wp + nt * 16 * C + ks * 32);
                acc6[nt] = __builtin_amdgcn_mfma_f32_16x16x32_bf16(a, b, acc6[nt], 0, 0, 0);
            }
        }
    }
    {   // Root path: own rows from global (bf16)
        int arow = r0 + l16;
        if (arow >= n) arow = n - 1;
        const u16* Xp = Xbf + (size_t)arow * C + quad * 8;
        const u16* Wp = WTR + l16 * C + quad * 8;
#pragma unroll
        for (int ks = 0; ks < 3; ks++) {
            short8 a = *(const short8*)(Xp + ks * 32);
#pragma unroll
            for (int nt = 0; nt < 6; nt++) {
                short8 b = *(const short8*)(Wp + nt * 16 * C + ks * 32);
                acc6[nt] = __builtin_amdgcn_mfma_f32_16x16x32_bf16(a, b, acc6[nt], 0, 0, 0);
            }
        }
    }

    // bias + relu in registers
#pragma unroll
    for (int nt = 0; nt < 6; nt++) {
        float bv = BIAS[nt * 16 + l16];
#pragma unroll
        for (int r = 0; r < 4; r++) {
            float v = acc6[nt][r] + bv;
            if (RELU) v = fmaxf(v, 0.f);
            acc6[nt][r] = v;
        }
    }
    __syncthreads();   // all sA (A-path) reads complete; safe to reuse

    const int nrow = min(64, n - row0);
    const int lr = w * 16 + quad * 4;          // this lane's tile rows lr..lr+3

    if constexpr (sizeof(OT) == 2) {
        // ---- bf16 output: stage 64x96 u16 (12 KB), write contiguous ----
        u16* so = sA;
#pragma unroll
        for (int nt = 0; nt < 6; nt++)
#pragma unroll
            for (int r = 0; r < 4; r++)
                so[(lr + r) * 96 + nt * 16 + l16] = f2bf(acc6[nt][r]);
        __syncthreads();
        {
            char* dst = (char*)Y + (size_t)row0 * 192;
            int nbytes = nrow * 192;
            for (int ofs = t * 16; ofs < nbytes; ofs += 4096)
                *(uint4*)(dst + ofs) = *(const uint4*)((const char*)sA + ofs);
        }
        if constexpr (WF8) {
            __syncthreads();
            u8* so8 = (u8*)sA;
#pragma unroll
            for (int nt = 0; nt < 6; nt++)
#pragma unroll
                for (int r = 0; r < 4; r++)
                    so8[(lr + r) * 96 + nt * 16 + l16] = f2fp8(acc6[nt][r]);
            __syncthreads();
            char* dst8 = (char*)Yf8 + (size_t)row0 * 96;
            int nb8 = nrow * 96;
            for (int ofs = t * 16; ofs < nb8; ofs += 4096)
                *(uint4*)(dst8 + ofs) = *(const uint4*)((const char*)sA + ofs);
        }
    } else {
        // ---- fp32 output: two 32-row halves (12 KB each) ----
        float* sof = (float*)sA;
#pragma unroll
        for (int half = 0; half < 2; half++) {
            if (half) __syncthreads();
            if ((w >> 1) == half) {
#pragma unroll
                for (int nt = 0; nt < 6; nt++)
#pragma unroll
                    for (int r = 0; r < 4; r++)
                        sof[((w & 1) * 16 + quad * 4 + r) * 96 + nt * 16 + l16] = acc6[nt][r];
            }
            __syncthreads();
            int rbase = row0 + half * 32;
            int nr = n - rbase;
            nr = nr < 0 ? 0 : (nr > 32 ? 32 : nr);
            char* dst = (char*)Y + (size_t)rbase * 384;
            int nbytes = nr * 384;
            for (int ofs = t * 16; ofs < nbytes; ofs += 4096)
                *(uint4*)(dst + ofs) = *(const uint4*)((const char*)sA + ofs);
        }
    }
}

// ---------------------------------------------------------------------------
extern "C" void kernel_launch(void* const* d_in, const int* in_sizes, int n_in,
                              void* d_out, int out_size, void* d_ws, size_t ws_size,
                              hipStream_t stream) {
    const float* x   = (const float*)d_in[0];
    const int*   ei  = (const int*)d_in[1];
    const float* W1  = (const float*)d_in[2];
    const float* Wr1 = (const float*)d_in[3];
    const float* b1  = (const float*)d_in[4];
    const float* W2  = (const float*)d_in[5];
    const float* Wr2 = (const float*)d_in[6];
    const float* b2  = (const float*)d_in[7];
    float* out = (float*)d_out;

    const int N = in_sizes[0] / C;      // 50000
    const int E = in_sizes[1] / 2;      // 800000
    const int* src = ei;
    const int* dst = ei + E;

    const int nbkt = (N + BKT_SIZE - 1) >> BKT_SHIFT;   // 98
    const int DB   = (E + EB - 1) / EB;                 // 391
    const int n16  = N * C / 16;
    const int CX   = (n16 + 255) / 256;                 // 1172
    int Npad = (N + 63) & ~63;

    // Workspace layout (16B alignment for vector sections)
    int*  blk_cnt = (int*)d_ws;                          // DB*128
    int*  blk_off = blk_cnt + DB * 128;                  // DB*128
    int*  deg     = blk_off + DB * 128;                  // Npad
    int*  row_off = deg + Npad;                          // Npad
    u32*  stage   = (u32*)(row_off + Npad);              // DB*EB
    u16*  csr     = (u16*)(stage + (size_t)DB * EB);     // nbkt*CAP u16
    u16*  xb      = csr + (((size_t)nbkt * CAP + 7) & ~(size_t)7);  // N*C bf16
    u16*  h1b     = xb + (size_t)N * C;                  // N*C bf16
    u16*  wt      = h1b + (size_t)N * C;                 // 4*C*C bf16
    u16 *wt1 = wt, *wtr1 = wt + C * C, *wt2 = wt + 2 * C * C, *wtr2 = wt + 3 * C * C;
    u8*   xf8     = (u8*)(wt + 4 * C * C);               // N*96 fp8
    u8*   h1f8    = xf8 + (size_t)N * 96;                // N*96 fp8

    const int grid64 = (N + 63) / 64;                    // 782

    binA_kernel<<<DB, 256, 0, stream>>>(src, dst, blk_cnt, blk_off, stage, E);
    binB_kernel<<<nbkt + CX + 4, 256, 0, stream>>>(stage, blk_cnt, blk_off,
                                                   deg, row_off, csr, N, DB, nbkt,
                                                   x, xb, xf8, n16, CX,
                                                   W1, Wr1, W2, Wr2, wt1, wtr1, wt2, wtr2);

    layer_kernel<true, true, u16><<<grid64, 256, 0, stream>>>(
        xb, xf8, row_off, deg, csr, wt1, wtr1, b1, h1b, h1f8, N);
    layer_kernel<false, false, float><<<grid64, 256, 0, stream>>>(
        h1b, h1f8, row_off, deg, csr, wt2, wtr2, b2, out, h1f8, N);
}

// Round 2
// 163.664 us; speedup vs baseline: 1.0057x; 1.0057x over previous
//
#include <hip/hip_runtime.h>
#include <hip/hip_cooperative_groups.h>

namespace cg = cooperative_groups;

#define C 96
#define BKT_SHIFT 9
#define BKT_SIZE 512    // nodes per bucket
#define CAP 10240       // per-bucket csr capacity (bucket mean 8163)
#define EB 2048         // edges per sort item
typedef unsigned char u8;
typedef unsigned short u16;
typedef unsigned int u32;
typedef __attribute__((ext_vector_type(8))) short short8;
typedef __attribute__((ext_vector_type(4))) float floatx4;
typedef __attribute__((ext_vector_type(2))) float floatx2;

__device__ inline u16 f2bf(float f) {
    union { float f; u32 u; } v; v.f = f;
    u32 r = v.u + 0x7fff + ((v.u >> 16) & 1);   // RNE
    return (u16)(r >> 16);
}
__device__ inline u32 pk4_fp8(float a, float b, float c, float d) {
    u32 w = 0;
    w = __builtin_amdgcn_cvt_pk_fp8_f32(a, b, w, false);
    w = __builtin_amdgcn_cvt_pk_fp8_f32(c, d, w, true);
    return w;
}
__device__ inline u8 f2fp8(float a) {
    return (u8)(__builtin_amdgcn_cvt_pk_fp8_f32(a, a, 0, false) & 0xff);
}

// ===========================================================================
// Phase bodies (shared between fused cooperative kernel and fallback kernels)
// ===========================================================================

// --- binA: counting-sort 2048 edges into 128 dst-buckets in LDS ------------
__device__ __forceinline__ void binA_body(int bid, int t,
        const int* __restrict__ src, const int* __restrict__ dst,
        int* __restrict__ blk_cnt, int* __restrict__ blk_off,
        u32* __restrict__ stage, int E,
        u32* s_word, int* s_cnt, int* s_inc) {
    int e0 = bid * EB;
    int cnt_here = min(EB, E - e0);

    for (int i = t; i < 128; i += 256) s_cnt[i] = 0;
    __syncthreads();

    int my_src[EB / 256], my_dl[EB / 256], my_b[EB / 256], my_rank[EB / 256];
    int nmine = 0;
#pragma unroll
    for (int k = 0; k < EB / 256; k++) {
        int i = t + k * 256;
        if (i < cnt_here) {
            int s = src[e0 + i], d = dst[e0 + i];
            int b = d >> BKT_SHIFT;
            my_src[nmine] = s;
            my_dl[nmine] = d & (BKT_SIZE - 1);
            my_b[nmine] = b;
            my_rank[nmine] = atomicAdd(&s_cnt[b], 1);
            nmine++;
        }
    }
    __syncthreads();

    if (t < 128) s_inc[t] = s_cnt[t];
    __syncthreads();
    for (int off = 1; off < 128; off <<= 1) {
        int x2 = (t >= off && t < 128) ? s_inc[t - off] : 0;
        __syncthreads();
        if (t < 128) s_inc[t] += x2;
        __syncthreads();
    }
    if (t < 128) {
        blk_cnt[bid * 128 + t] = s_cnt[t];
        blk_off[bid * 128 + t] = s_inc[t] - s_cnt[t];
    }

    for (int k = 0; k < nmine; k++) {
        int b = my_b[k];
        int slot = (s_inc[b] - s_cnt[b]) + my_rank[k];
        s_word[slot] = ((u32)my_dl[k] << 16) | (u32)my_src[k];
    }
    __syncthreads();

    for (int i = t; i < cnt_here; i += 256) stage[(size_t)bid * EB + i] = s_word[i];
}

// --- x -> bf16 + fp8 conversion, one 256-item chunk ------------------------
__device__ __forceinline__ void convert_chunk(int cc, int t,
        const float* __restrict__ x, u16* __restrict__ xb,
        u8* __restrict__ xf8, int n16) {
    int i = cc * 256 + t;
    if (i >= n16) return;
    const float4* p = (const float4*)x + (size_t)i * 4;
    float4 a = p[0], b = p[1], c = p[2], d = p[3];
    short8 o0, o1;
    o0[0] = (short)f2bf(a.x); o0[1] = (short)f2bf(a.y);
    o0[2] = (short)f2bf(a.z); o0[3] = (short)f2bf(a.w);
    o0[4] = (short)f2bf(b.x); o0[5] = (short)f2bf(b.y);
    o0[6] = (short)f2bf(b.z); o0[7] = (short)f2bf(b.w);
    o1[0] = (short)f2bf(c.x); o1[1] = (short)f2bf(c.y);
    o1[2] = (short)f2bf(c.z); o1[3] = (short)f2bf(c.w);
    o1[4] = (short)f2bf(d.x); o1[5] = (short)f2bf(d.y);
    o1[6] = (short)f2bf(d.z); o1[7] = (short)f2bf(d.w);
    *(short8*)(xb + (size_t)i * 16) = o0;
    *(short8*)(xb + (size_t)i * 16 + 8) = o1;
    uint4 f8;
    f8.x = pk4_fp8(a.x, a.y, a.z, a.w);
    f8.y = pk4_fp8(b.x, b.y, b.z, b.w);
    f8.z = pk4_fp8(c.x, c.y, c.z, c.w);
    f8.w = pk4_fp8(d.x, d.y, d.z, d.w);
    *(uint4*)(xf8 + (size_t)i * 16) = f8;
}

// --- W -> bf16 transpose ----------------------------------------------------
__device__ __forceinline__ void wtrans_body(int t, const float* __restrict__ W,
                                            u16* __restrict__ T) {
    for (int i = t; i < C * C; i += 256) {
        int k = i / C, n = i - k * C;
        T[n * C + k] = f2bf(W[i]);
    }
}

// --- bucket CSR build -------------------------------------------------------
__device__ __forceinline__ void bucket_body(int b, int t,
        const u32* __restrict__ stage, const int* __restrict__ blk_cnt,
        const int* __restrict__ blk_off, int* __restrict__ deg,
        int* __restrict__ row_off, u16* __restrict__ csr, int N, int DB,
        int* cnt, int* cur, int* ssum) {
    int n0 = b << BKT_SHIFT;
    int nn = min(BKT_SIZE, N - n0);
    int s0 = b * CAP;

    for (int i = t; i < BKT_SIZE; i += 256) cnt[i] = 0;
    __syncthreads();

    for (int i = t; i < DB; i += 256) {
        int len = blk_cnt[i * 128 + b];
        const u32* run = stage + (size_t)i * EB + blk_off[i * 128 + b];
        for (int j = 0; j < len; j++) atomicAdd(&cnt[run[j] >> 16], 1);
    }
    __syncthreads();

    int a0 = cnt[2 * t], a1 = cnt[2 * t + 1];
    ssum[t] = a0 + a1;
    __syncthreads();
    for (int off = 1; off < 256; off <<= 1) {
        int x2 = (t >= off) ? ssum[t - off] : 0;
        __syncthreads();
        ssum[t] += x2;
        __syncthreads();
    }
    int excl = ssum[t] - (a0 + a1);
    if (2 * t < nn) { deg[n0 + 2 * t] = a0; row_off[n0 + 2 * t] = s0 + excl; }
    if (2 * t + 1 < nn) { deg[n0 + 2 * t + 1] = a1; row_off[n0 + 2 * t + 1] = s0 + excl + a0; }
    __syncthreads();
    cur[2 * t] = s0 + excl;
    cur[2 * t + 1] = s0 + excl + a0;
    __syncthreads();

    for (int i = t; i < DB; i += 256) {
        int len = blk_cnt[i * 128 + b];
        const u32* run = stage + (size_t)i * EB + blk_off[i * 128 + b];
        for (int j = 0; j < len; j++) {
            u32 w = run[j];
            int p = atomicAdd(&cur[w >> 16], 1);
            csr[p] = (u16)(w & 0xffffu);
        }
    }
}

// --- fused layer: Y = (RELU?)(mean_agg(X)@WA + X@WR + BIAS), 64 nodes ------
template <bool RELU, bool WF8, typename OT>
__device__ __forceinline__ void layer_body(int bid, int t,
        const u16* __restrict__ Xbf, const u8* __restrict__ Xf8,
        const int* __restrict__ row_off, const int* __restrict__ deg,
        const u16* __restrict__ csr, const u16* __restrict__ WTA,
        const u16* __restrict__ WTR, const float* __restrict__ BIAS,
        OT* __restrict__ Y, u8* __restrict__ Yf8, int n,
        u16* sA, int* s_dg, int* s_perm) {
    const int row0 = bid * 64;

    // Phase 0: degree-rank permutation
    if (t < 64) {
        int node = row0 + t;
        s_dg[t] = (node < n) ? deg[node] : 0;
    }
    __syncthreads();
    if (t < 64) {
        int di = s_dg[t];
        int r = 0;
#pragma unroll 8
        for (int j = 0; j < 64; j++) {
            int dj = s_dg[j];
            r += (dj < di) || (dj == di && j < t);
        }
        s_perm[r] = t;
    }
    __syncthreads();

    // Phase 1: fp8 gather-mean (4 lanes/node, 24ch each, pipelined quads)
    // lane q owns channels [16q,16q+16) (acc[0..15]) and [64+8q,72+8q) (acc[16..23])
    {
        int nl = s_perm[t >> 2];
        int node = row0 + nl;
        int q = t & 3;
        float acc[24];
#pragma unroll
        for (int i = 0; i < 24; i++) acc[i] = 0.f;
        int d = 0, start = 0;
        if (node < n) { start = row_off[node]; d = s_dg[nl]; }
        const int off4 = q * 16;        // dwordx4 slice offset
        const int off2 = 64 + q * 8;    // dwordx2 slice offset

        int j = 0;
        if (d >= 4) {
            int si[4];
#pragma unroll
            for (int k = 0; k < 4; k++) si[k] = csr[start + k];
            for (; j + 8 <= d; j += 4) {
                uint4 va[4];
                uint2 vb[4];
#pragma unroll
                for (int k = 0; k < 4; k++) {
                    const u8* p = Xf8 + (size_t)si[k] * 96;
                    va[k] = *(const uint4*)(p + off4);
                    vb[k] = *(const uint2*)(p + off2);
                }
                int sn[4];    // prefetch next quad's indices before consuming
#pragma unroll
                for (int k = 0; k < 4; k++) sn[k] = csr[start + j + 4 + k];
#pragma unroll
                for (int k = 0; k < 4; k++) {
                    u32 ws[6] = {va[k].x, va[k].y, va[k].z,
                                 va[k].w, vb[k].x, vb[k].y};
#pragma unroll
                    for (int i = 0; i < 6; i++) {
                        floatx2 lo = __builtin_amdgcn_cvt_pk_f32_fp8(ws[i], false);
                        floatx2 hi = __builtin_amdgcn_cvt_pk_f32_fp8(ws[i], true);
                        acc[4 * i]     += lo[0];
                        acc[4 * i + 1] += lo[1];
                        acc[4 * i + 2] += hi[0];
                        acc[4 * i + 3] += hi[1];
                    }
                }
#pragma unroll
                for (int k = 0; k < 4; k++) si[k] = sn[k];
            }
            {   // drain the in-flight quad
                uint4 va[4];
                uint2 vb[4];
#pragma unroll
                for (int k = 0; k < 4; k++) {
                    const u8* p = Xf8 + (size_t)si[k] * 96;
                    va[k] = *(const uint4*)(p + off4);
                    vb[k] = *(const uint2*)(p + off2);
                }
#pragma unroll
                for (int k = 0; k < 4; k++) {
                    u32 ws[6] = {va[k].x, va[k].y, va[k].z,
                                 va[k].w, vb[k].x, vb[k].y};
#pragma unroll
                    for (int i = 0; i < 6; i++) {
                        floatx2 lo = __builtin_amdgcn_cvt_pk_f32_fp8(ws[i], false);
                        floatx2 hi = __builtin_amdgcn_cvt_pk_f32_fp8(ws[i], true);
                        acc[4 * i]     += lo[0];
                        acc[4 * i + 1] += lo[1];
                        acc[4 * i + 2] += hi[0];
                        acc[4 * i + 3] += hi[1];
                    }
                }
                j += 4;
            }
        }
        for (; j < d; j++) {
            const u8* p = Xf8 + (size_t)csr[start + j] * 96;
            uint4 va = *(const uint4*)(p + off4);
            uint2 vb = *(const uint2*)(p + off2);
            u32 ws[6] = {va.x, va.y, va.z, va.w, vb.x, vb.y};
#pragma unroll
            for (int i = 0; i < 6; i++) {
                floatx2 lo = __builtin_amdgcn_cvt_pk_f32_fp8(ws[i], false);
                floatx2 hi = __builtin_amdgcn_cvt_pk_f32_fp8(ws[i], true);
                acc[4 * i]     += lo[0];
                acc[4 * i + 1] += lo[1];
                acc[4 * i + 2] += hi[0];
                acc[4 * i + 3] += hi[1];
            }
        }
        float inv = 1.0f / fmaxf((float)d, 1.0f);
        u16* dl = sA + nl * 104;
        short8 o0, o1, o2;
#pragma unroll
        for (int i = 0; i < 8; i++) {
            o0[i] = (short)f2bf(acc[i] * inv);
            o1[i] = (short)f2bf(acc[8 + i] * inv);
            o2[i] = (short)f2bf(acc[16 + i] * inv);
        }
        *(short8*)(dl + q * 16) = o0;          // channels 16q..16q+7
        *(short8*)(dl + q * 16 + 8) = o1;      // channels 16q+8..16q+15
        *(short8*)(dl + 64 + q * 8) = o2;      // channels 64+8q..64+8q+7
    }
    __syncthreads();

    // Phase 2: dual MFMA GEMM
    const int lane = t & 63;
    const int w = t >> 6;
    const int quad = lane >> 4;
    const int l16 = lane & 15;
    const int r0 = row0 + w * 16;

    floatx4 acc6[6];
#pragma unroll
    for (int i = 0; i < 6; i++) acc6[i] = (floatx4){0.f, 0.f, 0.f, 0.f};

    {   // A-path: aggregated tile from LDS
        const u16* Ap = sA + (w * 16 + l16) * 104 + quad * 8;
        const u16* Wp = WTA + l16 * C + quad * 8;
#pragma unroll
        for (int ks = 0; ks < 3; ks++) {
            short8 a = *(const short8*)(Ap + ks * 32);
#pragma unroll
            for (int nt = 0; nt < 6; nt++) {
                short8 b = *(const short8*)(Wp + nt * 16 * C + ks * 32);
                acc6[nt] = __builtin_amdgcn_mfma_f32_16x16x32_bf16(a, b, acc6[nt], 0, 0, 0);
            }
        }
    }
    {   // Root path: own rows from global (bf16)
        int arow = r0 + l16;
        if (arow >= n) arow = n - 1;
        const u16* Xp = Xbf + (size_t)arow * C + quad * 8;
        const u16* Wp = WTR + l16 * C + quad * 8;
#pragma unroll
        for (int ks = 0; ks < 3; ks++) {
            short8 a = *(const short8*)(Xp + ks * 32);
#pragma unroll
            for (int nt = 0; nt < 6; nt++) {
                short8 b = *(const short8*)(Wp + nt * 16 * C + ks * 32);
                acc6[nt] = __builtin_amdgcn_mfma_f32_16x16x32_bf16(a, b, acc6[nt], 0, 0, 0);
            }
        }
    }

    // bias + relu in registers
#pragma unroll
    for (int nt = 0; nt < 6; nt++) {
        float bv = BIAS[nt * 16 + l16];
#pragma unroll
        for (int r = 0; r < 4; r++) {
            float v = acc6[nt][r] + bv;
            if (RELU) v = fmaxf(v, 0.f);
            acc6[nt][r] = v;
        }
    }
    __syncthreads();   // all sA (A-path) reads complete; safe to reuse

    const int nrow = min(64, n - row0);
    const int lr = w * 16 + quad * 4;          // this lane's tile rows lr..lr+3

    if constexpr (sizeof(OT) == 2) {
        // ---- bf16 output: stage 64x96 u16 (12 KB), write contiguous ----
        u16* so = sA;
#pragma unroll
        for (int nt = 0; nt < 6; nt++)
#pragma unroll
            for (int r = 0; r < 4; r++)
                so[(lr + r) * 96 + nt * 16 + l16] = f2bf(acc6[nt][r]);
        __syncthreads();
        {
            char* dstp = (char*)Y + (size_t)row0 * 192;
            int nbytes = nrow * 192;
            for (int ofs = t * 16; ofs < nbytes; ofs += 4096)
                *(uint4*)(dstp + ofs) = *(const uint4*)((const char*)sA + ofs);
        }
        if constexpr (WF8) {
            __syncthreads();
            u8* so8 = (u8*)sA;
#pragma unroll
            for (int nt = 0; nt < 6; nt++)
#pragma unroll
                for (int r = 0; r < 4; r++)
                    so8[(lr + r) * 96 + nt * 16 + l16] = f2fp8(acc6[nt][r]);
            __syncthreads();
            char* dst8 = (char*)Yf8 + (size_t)row0 * 96;
            int nb8 = nrow * 96;
            for (int ofs = t * 16; ofs < nb8; ofs += 4096)
                *(uint4*)(dst8 + ofs) = *(const uint4*)((const char*)sA + ofs);
        }
    } else {
        // ---- fp32 output: two 32-row halves (12 KB each) ----
        float* sof = (float*)sA;
#pragma unroll
        for (int half = 0; half < 2; half++) {
            if (half) __syncthreads();
            if ((w >> 1) == half) {
#pragma unroll
                for (int nt = 0; nt < 6; nt++)
#pragma unroll
                    for (int r = 0; r < 4; r++)
                        sof[((w & 1) * 16 + quad * 4 + r) * 96 + nt * 16 + l16] = acc6[nt][r];
            }
            __syncthreads();
            int rbase = row0 + half * 32;
            int nr = n - rbase;
            nr = nr < 0 ? 0 : (nr > 32 ? 32 : nr);
            char* dstp = (char*)Y + (size_t)rbase * 384;
            int nbytes = nr * 384;
            for (int ofs = t * 16; ofs < nbytes; ofs += 4096)
                *(uint4*)(dstp + ofs) = *(const uint4*)((const char*)sA + ofs);
        }
    }
}

// ===========================================================================
// Fused cooperative kernel: P0 binA+convert+Wtrans | P1 bucketCSR+convert |
// P2 layer1 | P3 layer2, separated by grid.sync().
// LDS: union of phase needs (13.8 KB max) -> 4 blocks/CU co-resident.
// ===========================================================================
__global__ __launch_bounds__(256, 4) void fused_kernel(
        const int* __restrict__ src, const int* __restrict__ dst,
        const float* __restrict__ x,
        const float* __restrict__ W1, const float* __restrict__ Wr1,
        const float* __restrict__ b1,
        const float* __restrict__ W2, const float* __restrict__ Wr2,
        const float* __restrict__ b2,
        int* blk_cnt, int* blk_off, int* deg, int* row_off,
        u32* stage, u16* csr, u16* xb, u8* xf8, u16* h1b, u8* h1f8,
        u16* wt1, u16* wtr1, u16* wt2, u16* wtr2,
        float* out, int N, int E, int DB, int nbkt, int n16, int CX) {
    __shared__ __align__(16) union {
        struct { u32 s_word[EB]; int s_cnt[128]; int s_inc[128]; } a;  // 9.2 KB
        struct { int cnt[BKT_SIZE]; int cur[BKT_SIZE]; int ssum[256]; } b;  // 5 KB
        struct { u16 sA[64 * 104]; int s_dg[64]; int s_perm[64]; } c;  // 13.8 KB
    } sm;
    const int bid = blockIdx.x;
    const int t = threadIdx.x;
    const int GRID = (int)gridDim.x;
    cg::grid_group grid = cg::this_grid();

    // ---- P0: sort items + early x-conversion + W transpose ----
    if (bid < DB) {
        binA_body(bid, t, src, dst, blk_cnt, blk_off, stage, E,
                  sm.a.s_word, sm.a.s_cnt, sm.a.s_inc);
    } else {
        int cc = bid - DB;
        if (cc < CX) convert_chunk(cc, t, x, xb, xf8, n16);
        if (cc < 4) {
            const float* W = cc == 0 ? W1 : cc == 1 ? Wr1 : cc == 2 ? W2 : Wr2;
            u16* T = cc == 0 ? wt1 : cc == 1 ? wtr1 : cc == 2 ? wt2 : wtr2;
            wtrans_body(t, W, T);
        }
    }
    grid.sync();

    // ---- P1: bucket CSR build + remaining x-conversion ----
    if (bid < nbkt) {
        bucket_body(bid, t, stage, blk_cnt, blk_off, deg, row_off, csr, N, DB,
                    sm.b.cnt, sm.b.cur, sm.b.ssum);
    } else {
        int p0 = GRID - DB;    // chunks already done in P0
        for (int cc = p0 + (bid - nbkt); cc < CX; cc += GRID - nbkt)
            convert_chunk(cc, t, x, xb, xf8, n16);
    }
    grid.sync();

    // ---- P2: layer 1 (relu, writes bf16 + fp8) ----
    layer_body<true, true, u16>(bid, t, xb, xf8, row_off, deg, csr,
                                wt1, wtr1, b1, h1b, h1f8, N,
                                sm.c.sA, sm.c.s_dg, sm.c.s_perm);
    grid.sync();

    // ---- P3: layer 2 (fp32 out) ----
    layer_body<false, false, float>(bid, t, h1b, h1f8, row_off, deg, csr,
                                    wt2, wtr2, b2, out, h1f8, N,
                                    sm.c.sA, sm.c.s_dg, sm.c.s_perm);
}

// ===========================================================================
// Fallback kernels (original 4-launch path, used if cooperative launch fails)
// ===========================================================================
__global__ __launch_bounds__(256) void binA_kernel(const int* __restrict__ src,
                                                   const int* __restrict__ dst,
                                                   int* __restrict__ blk_cnt,
                                                   int* __restrict__ blk_off,
                                                   u32* __restrict__ stage, int E) {
    __shared__ u32 s_word[EB];
    __shared__ int s_cnt[128];
    __shared__ int s_inc[128];
    binA_body(blockIdx.x, threadIdx.x, src, dst, blk_cnt, blk_off, stage, E,
              s_word, s_cnt, s_inc);
}

__global__ __launch_bounds__(256) void binB_kernel(const u32* __restrict__ stage,
                                                   const int* __restrict__ blk_cnt,
                                                   const int* __restrict__ blk_off,
                                                   int* __restrict__ deg,
                                                   int* __restrict__ row_off,
                                                   u16* __restrict__ csr, int N, int DB,
                                                   int nbkt,
                                                   const float* __restrict__ x,
                                                   u16* __restrict__ xb,
                                                   u8* __restrict__ xf8, int n16, int CX,
                                                   const float* W0, const float* W1,
                                                   const float* W2, const float* W3,
                                                   u16* T0, u16* T1, u16* T2, u16* T3) {
    int bid = blockIdx.x;
    int t = threadIdx.x;
    if (bid >= nbkt) {
        if (bid < nbkt + CX) {
            convert_chunk(bid - nbkt, t, x, xb, xf8, n16);
        } else {
            int w = bid - nbkt - CX;
            const float* W = w == 0 ? W0 : w == 1 ? W1 : w == 2 ? W2 : W3;
            u16* T = w == 0 ? T0 : w == 1 ? T1 : w == 2 ? T2 : T3;
            wtrans_body(t, W, T);
        }
        return;
    }
    __shared__ int cnt[BKT_SIZE];
    __shared__ int cur[BKT_SIZE];
    __shared__ int ssum[256];
    bucket_body(bid, t, stage, blk_cnt, blk_off, deg, row_off, csr, N, DB,
                cnt, cur, ssum);
}

template <bool RELU, bool WF8, typename OT>
__global__ __launch_bounds__(256, 4) void layer_kernel(const u16* __restrict__ Xbf,
                                                       const u8* __restrict__ Xf8,
                                                       const int* __restrict__ row_off,
                                                       const int* __restrict__ deg,
                                                       const u16* __restrict__ csr,
                                                       const u16* __restrict__ WTA,
                                                       const u16* __restrict__ WTR,
                                                       const float* __restrict__ BIAS,
                                                       OT* __restrict__ Y,
                                                       u8* __restrict__ Yf8, int n) {
    __shared__ __align__(16) u16 sA[64 * 104];
    __shared__ int s_dg[64];
    __shared__ int s_perm[64];
    layer_body<RELU, WF8, OT>(blockIdx.x, threadIdx.x, Xbf, Xf8, row_off, deg, csr,
                              WTA, WTR, BIAS, Y, Yf8, n, sA, s_dg, s_perm);
}

// ---------------------------------------------------------------------------
extern "C" void kernel_launch(void* const* d_in, const int* in_sizes, int n_in,
                              void* d_out, int out_size, void* d_ws, size_t ws_size,
                              hipStream_t stream) {
    const float* x   = (const float*)d_in[0];
    const int*   ei  = (const int*)d_in[1];
    const float* W1  = (const float*)d_in[2];
    const float* Wr1 = (const float*)d_in[3];
    const float* b1  = (const float*)d_in[4];
    const float* W2  = (const float*)d_in[5];
    const float* Wr2 = (const float*)d_in[6];
    const float* b2  = (const float*)d_in[7];
    float* out = (float*)d_out;

    int N = in_sizes[0] / C;      // 50000
    int E = in_sizes[1] / 2;      // 800000
    const int* src = ei;
    const int* dst = ei + E;

    int nbkt = (N + BKT_SIZE - 1) >> BKT_SHIFT;   // 98
    int DB   = (E + EB - 1) / EB;                 // 391
    int n16  = N * C / 16;
    int CX   = (n16 + 255) / 256;                 // 1172
    int Npad = (N + 63) & ~63;

    // Workspace layout (16B alignment for vector sections)
    int*  blk_cnt = (int*)d_ws;                          // DB*128
    int*  blk_off = blk_cnt + DB * 128;                  // DB*128
    int*  deg     = blk_off + DB * 128;                  // Npad
    int*  row_off = deg + Npad;                          // Npad
    u32*  stage   = (u32*)(row_off + Npad);              // DB*EB
    u16*  csr     = (u16*)(stage + (size_t)DB * EB);     // nbkt*CAP u16
    u16*  xb      = csr + (((size_t)nbkt * CAP + 7) & ~(size_t)7);  // N*C bf16
    u16*  h1b     = xb + (size_t)N * C;                  // N*C bf16
    u16*  wt      = h1b + (size_t)N * C;                 // 4*C*C bf16
    u16 *wt1 = wt, *wtr1 = wt + C * C, *wt2 = wt + 2 * C * C, *wtr2 = wt + 3 * C * C;
    u8*   xf8     = (u8*)(wt + 4 * C * C);               // N*96 fp8
    u8*   h1f8    = xf8 + (size_t)N * 96;                // N*96 fp8

    const int grid64 = (N + 63) / 64;                    // 782

    // ---- try fused cooperative path ----
    static int coop = -1;
    if (coop < 0) {
        int dev = 0;
        (void)hipGetDevice(&dev);
        int v = 0;
        if (hipDeviceGetAttribute(&v, hipDeviceAttributeCooperativeLaunch, dev) != hipSuccess)
            v = 0;
        coop = v;
    }
    if (coop) {
        void* args[] = {
            (void*)&src, (void*)&dst, (void*)&x,
            (void*)&W1, (void*)&Wr1, (void*)&b1,
            (void*)&W2, (void*)&Wr2, (void*)&b2,
            (void*)&blk_cnt, (void*)&blk_off, (void*)&deg, (void*)&row_off,
            (void*)&stage, (void*)&csr, (void*)&xb, (void*)&xf8,
            (void*)&h1b, (void*)&h1f8,
            (void*)&wt1, (void*)&wtr1, (void*)&wt2, (void*)&wtr2,
            (void*)&out, (void*)&N, (void*)&E, (void*)&DB, (void*)&nbkt,
            (void*)&n16, (void*)&CX};
        hipError_t e = hipLaunchCooperativeKernel((const void*)fused_kernel,
                                                  dim3(grid64), dim3(256),
                                                  args, 0, stream);
        if (e == hipSuccess) return;
        (void)hipGetLastError();   // clear error, fall through
        coop = 0;
    }

    // ---- fallback: original 4-kernel path ----
    binA_kernel<<<DB, 256, 0, stream>>>(src, dst, blk_cnt, blk_off, stage, E);
    binB_kernel<<<nbkt + CX + 4, 256, 0, stream>>>(stage, blk_cnt, blk_off,
                                                   deg, row_off, csr, N, DB, nbkt,
                                                   x, xb, xf8, n16, CX,
                                                   W1, Wr1, W2, Wr2, wt1, wtr1, wt2, wtr2);
    layer_kernel<true, true, u16><<<grid64, 256, 0, stream>>>(
        xb, xf8, row_off, deg, csr, wt1, wtr1, b1, h1b, h1f8, N);
    layer_kernel<false, false, float><<<grid64, 256, 0, stream>>>(
        h1b, h1f8, row_off, deg, csr, wt2, wtr2, b2, out, h1f8, N);
}